// Round 13
// baseline (1783.995 us; speedup 1.0000x reference)
//
#include <hip/hip_runtime.h>
#include <hip/hip_cooperative_groups.h>
#include <math.h>

namespace cg = cooperative_groups;

#define TT 10
#define BB 32
#define CIN 3
#define COUT 64
#define HH 64
#define WW 64
#define HW (HH*WW)           // 4096
#define DECAY 0.2f
#define INH 1.625f
#define RS 68                // LDS row stride (floats): 272B, 16B-aligned

__device__ __forceinline__ unsigned int enc_f(float f) {
    unsigned int u = __float_as_uint(f);
    return (u & 0x80000000u) ? ~u : (u | 0x80000000u);
}
__device__ __forceinline__ float dec_f(unsigned int u) {
    u = (u & 0x80000000u) ? (u & 0x7FFFFFFFu) : ~u;
    return __uint_as_float(u);
}

// Stage NROWS rows of x into LDS rows of stride RS (slot cl = x col cl-1,
// cl==0 / cl>=65 zero pad). Row r -> (ci = r/RPC, gh = ghbase + r%RPC - 1).
template <int NROWS, int RPC>
__device__ __forceinline__ void stage_x(float* sxf, const float* xb,
                                        int ghbase, int tid) {
    const int NSLOT = NROWS * RS;
    const int NITER = (NSLOT + 255) / 256;
    float vals[NITER];
    #pragma unroll
    for (int it = 0; it < NITER; it++) {
        int l = tid + it * 256;
        float v = 0.f;
        if (l < NSLOT) {
            int row = l / RS, cl = l % RS;
            int ci = row / RPC, rr = row % RPC;
            int gh = ghbase + rr - 1;
            if (cl >= 1 && cl <= 64 && gh >= 0 && gh < HH)
                v = xb[ci * HW + gh * WW + (cl - 1)];
        }
        vals[it] = v;
    }
    #pragma unroll
    for (int it = 0; it < NITER; it++) {
        int l = tid + it * 256;
        if (l < NSLOT) sxf[l] = vals[it];
    }
}

// Conv core (r10-proven, bitwise-stable k-order): 16 px from p0 (16-aligned),
// lane = channel. Per (ci,kh) row: 18 floats via wave-uniform broadcast
// b128/b64 reads; 48 FMA over 16 independent accs. fmaf order: q,kw ascending.
__device__ __forceinline__ void conv16(const float* __restrict__ sxbase,
                                       const int* rows, const float* w,
                                       int p0, float acc[16]) {
    #pragma unroll
    for (int j = 0; j < 16; j++) acc[j] = 0.f;
    #pragma unroll
    for (int q = 0; q < 9; q++) {            // q = ci*3 + kh
        const float* rp = sxbase + rows[q] * RS + p0;
        float xr[18];
        float4 a0 = *(const float4*)(rp + 0);
        float4 a1 = *(const float4*)(rp + 4);
        float4 a2 = *(const float4*)(rp + 8);
        float4 a3 = *(const float4*)(rp + 12);
        float2 a4 = *(const float2*)(rp + 16);
        xr[0]=a0.x; xr[1]=a0.y; xr[2]=a0.z; xr[3]=a0.w;
        xr[4]=a1.x; xr[5]=a1.y; xr[6]=a1.z; xr[7]=a1.w;
        xr[8]=a2.x; xr[9]=a2.y; xr[10]=a2.z; xr[11]=a2.w;
        xr[12]=a3.x; xr[13]=a3.y; xr[14]=a3.z; xr[15]=a3.w;
        xr[16]=a4.x; xr[17]=a4.y;
        const float w0 = w[q * 3 + 0];
        const float w1 = w[q * 3 + 1];
        const float w2 = w[q * 3 + 2];
        #pragma unroll
        for (int j = 0; j < 16; j++) {
            acc[j] = fmaf(w0, xr[j],     acc[j]);
            acc[j] = fmaf(w1, xr[j + 1], acc[j]);
            acc[j] = fmaf(w2, xr[j + 2], acc[j]);
        }
    }
}

// ---------------------------------------------------------------------------
// SINGLE cooperative kernel: conv once per (t,px), no i round-trip, thr via
// atomicMax + grid.sync per step. Grid 1024 = 4 blocks/CU exactly (guaranteed
// by __launch_bounds__(256,4): VGPR<=128; LDS 36.9KB*4 = 148KB <= 160KB).
// Block = 2 rows (b, h0=2*hp); wave = 32 px of one row; lane = channel;
// mem[32]/thread in registers across all t; conv parked in LDS sI across the
// grid sync.
// ---------------------------------------------------------------------------
__global__ __launch_bounds__(256, 4) void snn_coop(
    const float* __restrict__ x,        // (T,B,3,64,64)
    const float* __restrict__ Wt,       // (64,3,3,3)
    float* __restrict__ out,            // (T,B,64,64,64)
    unsigned int* __restrict__ thr_raw) // (T,64) pre-zeroed
{
    __shared__ float sx[12][RS];        // 4 rows (h0-1..h0+2) x 3 ci
    __shared__ float sI[128][64];       // conv result: [row*64+px][c]
    __shared__ float wmax[4][COUT];

    cg::grid_group grid = cg::this_grid();

    const int tid  = threadIdx.x;
    const int lane = tid & 63;          // channel
    const int wave = tid >> 6;
    const int row  = wave >> 1;         // 0/1: which of the block's 2 rows
    const int p0   = __builtin_amdgcn_readfirstlane((wave & 1) * 32);
    const int b    = blockIdx.x >> 5;
    const int h0   = (blockIdx.x & 31) * 2;
    const int h    = h0 + row;

    float w[27];
    #pragma unroll
    for (int k = 0; k < 27; k++) w[k] = Wt[lane * 27 + k];

    int rows[9];                        // (ci,kh) -> sx row = ci*4 + row + kh
    #pragma unroll
    for (int ci = 0; ci < CIN; ci++)
        #pragma unroll
        for (int kh = 0; kh < 3; kh++)
            rows[ci * 3 + kh] = ci * 4 + row + kh;

    float mem[32];
    #pragma unroll
    for (int j = 0; j < 32; j++) mem[j] = 0.f;

    #pragma unroll 1
    for (int t = 0; t < TT; t++) {
        __syncthreads();   // prior-step sx/sI/wmax reads complete

        const float* xb = x + ((size_t)t * BB + b) * (CIN * HW);
        stage_x<12, 4>(&sx[0][0], xb, h0, tid);
        __syncthreads();

        // ---- conv: 2 chunks of 16 px; park in sI; per-channel max ----
        float mx = -INFINITY;
        #pragma unroll 1
        for (int cc = 0; cc < 2; cc++) {
            float acc[16];
            conv16(&sx[0][0], rows, w, p0 + cc * 16, acc);
            #pragma unroll
            for (int j = 0; j < 16; j++) {
                sI[row * 64 + p0 + cc * 16 + j][lane] = acc[j];
                mx = fmaxf(mx, acc[j]);
            }
        }
        wmax[wave][lane] = mx;
        __syncthreads();

        if (wave == 0) {
            float m = fmaxf(fmaxf(wmax[0][lane], wmax[1][lane]),
                            fmaxf(wmax[2][lane], wmax[3][lane]));
            unsigned int e = enc_f(m);
            unsigned int cur = __hip_atomic_load(&thr_raw[t * COUT + lane],
                                                 __ATOMIC_RELAXED,
                                                 __HIP_MEMORY_SCOPE_AGENT);
            if (e > cur) atomicMax(&thr_raw[t * COUT + lane], e);
        }

        grid.sync();   // thr[t] complete across all blocks

        unsigned int u = __hip_atomic_load(&thr_raw[t * COUT + lane],
                                           __ATOMIC_RELAXED,
                                           __HIP_MEMORY_SCOPE_AGENT);
        float thr   = dec_f(u) + 1e-4f;
        float sinv  = 8.0f / thr;
        float s04   = 0.4f * thr;
        float sinh_ = INH * thr;

        // ---- ASF + LIF + ballot-WTA over this wave's 32 px ----
        unsigned int fmask = 0;
        #pragma unroll
        for (int j = 0; j < 32; j++) {
            float iv  = sI[row * 64 + p0 + j][lane];
            float cur = fmaxf(iv, 0.f);
            float z   = (cur - s04) * sinv;
            float sig = 1.0f / (1.0f + expf(-z));
            float m   = mem[j] * DECAY + thr * sig;
            int   sp  = m > thr;
            float score = sp ? m : 0.f;

            unsigned long long blt = __ballot(sp);
            int fr = 0, sp_any = 0;
            if (blt) {   // wave-uniform, rare
                float bs = score;
                int   bc = lane;
                #pragma unroll
                for (int off = 32; off > 0; off >>= 1) {
                    float so = __shfl_xor(bs, off, 64);
                    int   co = __shfl_xor(bc, off, 64);
                    if (so > bs || (so == bs && co < bc)) { bs = so; bc = co; }
                }
                sp_any = __shfl(sp, bc, 64);   // winner's spike = any_sp
                fr     = (lane == bc) && sp;
            }
            mem[j] = fr ? 0.f : (m - (sp_any ? sinh_ : 0.f));
            if (fr) fmask |= (1u << j);
        }

        // wave-local stores: lane's channel row, its 32 px, 8x dwordx4
        float* ob = out + (((size_t)t * BB + b) * COUT + lane) * HW
                        + h * WW + p0;
        #pragma unroll
        for (int g = 0; g < 8; g++) {
            float4 v;
            v.x = (fmask >> (g * 4 + 0)) & 1 ? 1.f : 0.f;
            v.y = (fmask >> (g * 4 + 1)) & 1 ? 1.f : 0.f;
            v.z = (fmask >> (g * 4 + 2)) & 1 ? 1.f : 0.f;
            v.w = (fmask >> (g * 4 + 3)) & 1 ? 1.f : 0.f;
            *(float4*)(ob + g * 4) = v;
        }
    }
}

// ---------------------------------------------------------------------------
// Fallback pair (r10-proven, 557 us, absmax 0.0) in case coop launch errors.
// ---------------------------------------------------------------------------
__global__ __launch_bounds__(256) void thr_kernel(
    const float* __restrict__ x, const float* __restrict__ Wt,
    unsigned int* __restrict__ thr_raw)
{
    __shared__ float sx[CIN * 6][RS];
    __shared__ float wmax[4][COUT];

    const int tid  = threadIdx.x;
    const int lane = tid & 63;
    const int wave = tid >> 6;
    const int h0   = blockIdx.x * 4;
    const int b    = blockIdx.y;
    const int t    = blockIdx.z;

    float w[27];
    #pragma unroll
    for (int k = 0; k < 27; k++) w[k] = Wt[lane * 27 + k];

    const float* xb = x + ((size_t)t * BB + b) * (CIN * HW);
    stage_x<CIN * 6, 6>(&sx[0][0], xb, h0, tid);
    __syncthreads();

    int rows[9];
    #pragma unroll
    for (int ci = 0; ci < CIN; ci++)
        #pragma unroll
        for (int kh = 0; kh < 3; kh++)
            rows[ci * 3 + kh] = ci * 6 + wave + kh;

    float mx = -INFINITY;
    #pragma unroll 1
    for (int cc = 0; cc < 4; cc++) {
        float acc[16];
        conv16(&sx[0][0], rows, w, cc * 16, acc);
        #pragma unroll
        for (int j = 0; j < 16; j++) mx = fmaxf(mx, acc[j]);
    }

    wmax[wave][lane] = mx;
    __syncthreads();
    if (wave == 0) {
        float m = fmaxf(fmaxf(wmax[0][lane], wmax[1][lane]),
                        fmaxf(wmax[2][lane], wmax[3][lane]));
        atomicMax(&thr_raw[t * COUT + lane], enc_f(m));
    }
}

__global__ __launch_bounds__(256) void lif_kernel(
    const float* __restrict__ x, const float* __restrict__ Wt,
    const unsigned int* __restrict__ thr_raw, float* __restrict__ out)
{
    __shared__ float sx[CIN * 3][RS];

    const int tid  = threadIdx.x;
    const int lane = tid & 63;
    const int wave = tid >> 6;
    const int p0   = __builtin_amdgcn_readfirstlane(wave * 16);
    const int b    = blockIdx.x >> 6;
    const int h    = blockIdx.x & 63;

    float w[27];
    #pragma unroll
    for (int k = 0; k < 27; k++) w[k] = Wt[lane * 27 + k];

    int rows[9];
    #pragma unroll
    for (int q = 0; q < 9; q++) rows[q] = q;

    float mem[16];
    #pragma unroll
    for (int j = 0; j < 16; j++) mem[j] = 0.f;

    #pragma unroll 1
    for (int t = 0; t < TT; t++) {
        __syncthreads();
        const float* xb = x + ((size_t)t * BB + b) * (CIN * HW);
        stage_x<CIN * 3, 3>(&sx[0][0], xb, h, tid);
        float thr   = dec_f(thr_raw[t * COUT + lane]) + 1e-4f;
        float sinv  = 8.0f / thr;
        float s04   = 0.4f * thr;
        float sinh_ = INH * thr;
        __syncthreads();

        float acc[16];
        conv16(&sx[0][0], rows, w, p0, acc);

        int fmask = 0;
        #pragma unroll
        for (int j = 0; j < 16; j++) {
            float cur = fmaxf(acc[j], 0.f);
            float z   = (cur - s04) * sinv;
            float sig = 1.0f / (1.0f + expf(-z));
            float m   = mem[j] * DECAY + thr * sig;
            int   sp  = m > thr;
            float score = sp ? m : 0.f;
            unsigned long long blt = __ballot(sp);
            int fr = 0, sp_any = 0;
            if (blt) {
                float bs = score;
                int   bc = lane;
                #pragma unroll
                for (int off = 32; off > 0; off >>= 1) {
                    float so = __shfl_xor(bs, off, 64);
                    int   co = __shfl_xor(bc, off, 64);
                    if (so > bs || (so == bs && co < bc)) { bs = so; bc = co; }
                }
                sp_any = __shfl(sp, bc, 64);
                fr     = (lane == bc) && sp;
            }
            mem[j] = fr ? 0.f : (m - (sp_any ? sinh_ : 0.f));
            if (fr) fmask |= (1 << j);
        }

        float* ob = out + (((size_t)t * BB + b) * COUT + lane) * HW
                        + h * WW + p0;
        #pragma unroll
        for (int g = 0; g < 4; g++) {
            float4 v;
            v.x = (fmask >> (g * 4 + 0)) & 1 ? 1.f : 0.f;
            v.y = (fmask >> (g * 4 + 1)) & 1 ? 1.f : 0.f;
            v.z = (fmask >> (g * 4 + 2)) & 1 ? 1.f : 0.f;
            v.w = (fmask >> (g * 4 + 3)) & 1 ? 1.f : 0.f;
            *(float4*)(ob + g * 4) = v;
        }
    }
}

// ---------------------------------------------------------------------------
extern "C" void kernel_launch(void* const* d_in, const int* in_sizes, int n_in,
                              void* d_out, int out_size, void* d_ws, size_t ws_size,
                              hipStream_t stream) {
    const float* x = (const float*)d_in[0];   // (T,B,3,64,64)
    const float* W = (const float*)d_in[1];   // (64,3,3,3)
    float* out     = (float*)d_out;           // (T,B,64,64,64)

    unsigned int* thr = (unsigned int*)d_ws;  // (T,64)
    hipMemsetAsync(thr, 0, TT * COUT * sizeof(unsigned int), stream);

    void* args[] = { (void*)&x, (void*)&W, (void*)&out, (void*)&thr };
    hipError_t err = hipLaunchCooperativeKernel((void*)snn_coop,
                                                dim3(1024), dim3(256),
                                                args, 0, stream);
    if (err != hipSuccess) {
        (void)hipGetLastError();   // clear sticky error, use proven fallback
        thr_kernel<<<dim3(HH / 4, BB, TT), 256, 0, stream>>>(x, W, thr);
        lif_kernel<<<dim3(BB * HH), 256, 0, stream>>>(x, W, thr, out);
    }
}